// Round 4
// baseline (326.398 us; speedup 1.0000x reference)
//
#include <hip/hip_runtime.h>

#define TSEQ   512
#define BATCH  4096
#define MROWS  16

typedef short bf16x8 __attribute__((ext_vector_type(8)));
typedef float f32x4  __attribute__((ext_vector_type(4)));
typedef float f32x2  __attribute__((ext_vector_type(2)));

#define NL2E  (-1.44269504f)
#define P2L2E (2.88539008f)

__device__ __forceinline__ unsigned short f2bf(float f) {
    unsigned int u = __builtin_bit_cast(unsigned int, f);
    return (unsigned short)((u + 0x8000u) >> 16);
}

// Gate math for TWO cells at once, vectorized as f32x2 (v_pk_* fp32).
// a,b pre-scaled accs: exp2(a0)=e^-i, exp2(a1)=e^-f, exp2(a2)=e^{2g},
// exp2(a3)=e^-o. C = cell-state pair scaled by 2*log2e.
__device__ __forceinline__ f32x2 cellupd2(const f32x4 a, const f32x4 b, f32x2& C) {
    f32x2 ei = {__builtin_amdgcn_exp2f(a[0]), __builtin_amdgcn_exp2f(b[0])};
    f32x2 ef = {__builtin_amdgcn_exp2f(a[1]), __builtin_amdgcn_exp2f(b[1])};
    f32x2 eg = {__builtin_amdgcn_exp2f(a[2]), __builtin_amdgcn_exp2f(b[2])};
    f32x2 eo = {__builtin_amdgcn_exp2f(a[3]), __builtin_amdgcn_exp2f(b[3])};
    f32x2 A  = 1.f + ei;
    f32x2 G1 = eg + 1.f;
    f32x2 F  = 1.f + ef;
    f32x2 t  = A * G1;
    f32x2 G2 = eg * P2L2E + (NL2E * 2.f);
    f32x2 num = C * t + G2 * F;
    f32x2 den = t * F;
    f32x2 r  = {__builtin_amdgcn_rcpf(den.x), __builtin_amdgcn_rcpf(den.y)};
    f32x2 Cn = num * r;
    Cn.x = fminf(Cn.x, 126.f);
    Cn.y = fminf(Cn.y, 126.f);
    C = Cn;
    f32x2 ec = {__builtin_amdgcn_exp2f(Cn.x), __builtin_amdgcn_exp2f(Cn.y)};
    f32x2 B  = 1.f + eo;
    f32x2 hn = ec - 1.f;
    f32x2 hd = B * (ec + 1.f);
    f32x2 rr = {__builtin_amdgcn_rcpf(hd.x), __builtin_amdgcn_rcpf(hd.y)};
    return hn * rr;
}

// ring/h2s rows: 64 bf16 = 128B, XOR swizzle byte ^= ((row&7)<<4) on write+read.
// xq: 64 slot-rows x 16 cols x 8 bf16 (16B frag), swizzle byte ^= ((t64&7)<<4).
// 8 waves, MERGED roles: every wave does L1 (t=s) AND L2 (t=s-1, lag 1) each
// slot. Slot s, p=(s+1)&1: read ring[p] (shared by both layers) + h2s[p^1];
// write ring[p^1] (h1_s) + h2s[p] (h2_{s-1}). Slots 0..512.

__global__ __launch_bounds__(512, 2) void lstm2_kernel(
    const float* __restrict__ x,
    const float* __restrict__ Wih0, const float* __restrict__ Whh0,
    const float* __restrict__ bih0, const float* __restrict__ bhh0,
    const float* __restrict__ Wih1, const float* __restrict__ Whh1,
    const float* __restrict__ bih1, const float* __restrict__ bhh1,
    const float* __restrict__ Wc1,  const float* __restrict__ bc1,
    const float* __restrict__ Wc2,  const float* __restrict__ bc2,
    float* __restrict__ out)
{
    __shared__ __align__(16) unsigned short ring[2][MROWS * 64];
    __shared__ __align__(16) unsigned short h2s[2][MROWS * 64];
    __shared__ __align__(16) unsigned short xq[64][128];   // 16 KB
    __shared__ float h2f[MROWS][65];
    __shared__ float hid[MROWS][33];

    const int tid  = threadIdx.x;
    const int wv   = tid >> 6;        // 0..7
    const int lane = tid & 63;
    const int col  = lane & 15;       // batch index (B-operand col / A-row)
    const int lg   = lane >> 4;       // k-group
    const int b0   = blockIdx.x * MROWS;
    const int sw   = (col & 7) << 4;

    for (int i = tid; i < 1024; i += 512) {
        ((unsigned int*)ring)[i] = 0u;
        ((unsigned int*)h2s)[i]  = 0u;
    }

    // ---- x chunk 0 convert (into xq rows 0..31) + chunk 1 prefetch ----
    const int xrow = tid >> 5;        // 0..15
    const int xt   = tid & 31;        // chunk-local timestep
    const float* xb = x + ((size_t)(b0 + xrow) * TSEQ + xt) * 3;
    float xr0 = xb[0], xr1 = xb[1], xr2 = xb[2];
    {
        bf16x8 xf = {(short)f2bf(xr0),(short)f2bf(xr1),(short)f2bf(xr2),0,0,0,0,0};
        *(bf16x8*)((char*)xq + (xt << 8) + ((xrow << 4) ^ ((xt & 7) << 4))) = xf;
    }
    xr0 = xb[96]; xr1 = xb[97]; xr2 = xb[98];
    __syncthreads();

    const int rd0 = (col * 128 +      lg * 16) ^ sw;
    const int rd1 = (col * 128 + 64 + lg * 16) ^ sw;

#define FLUSH(S) do { \
    if (((S) & 31) == 16 && (S) < 480) { \
        const int c1_ = ((S) >> 5) + 1; \
        const int t64_ = ((c1_ & 1) << 5) + xt; \
        bf16x8 xf_ = {(short)f2bf(xr0),(short)f2bf(xr1),(short)f2bf(xr2),0,0,0,0,0}; \
        *(bf16x8*)((char*)xq + (t64_ << 8) + ((xrow << 4) ^ ((xt & 7) << 4))) = xf_; \
        if (c1_ < 15) { const float* p_ = xb + (c1_ + 1) * 96; xr0 = p_[0]; xr1 = p_[1]; xr2 = p_[2]; } \
    } \
} while(0)

#define XQRD(S) (*(const bf16x8*)((const char*)xq + ((((S)&63)) << 8) + ((col << 4) ^ (((S)&7) << 4))))
#define MM(A,B,C) __builtin_amdgcn_mfma_f32_16x16x32_bf16((A),(B),(C),0,0,0)

    // ===== weights: BOTH layers per wave; lane owns units u = 16*lg + 2*wq + {0,1} =====
    const int wq = wv;
    const int ga = col & 3;
    const float sca = (ga == 2) ? P2L2E : NL2E;
    bf16x8 WfL1[2][3];
    f32x4 biaL1[2];
#pragma unroll
    for (int tt = 0; tt < 2; ++tt) {
        const int n = ga * 64 + 16 * (col >> 2) + 2 * wq + tt;
#pragma unroll
        for (int f = 0; f < 3; ++f)
#pragma unroll
            for (int i = 0; i < 8; ++i) {
                const int k = f * 32 + lg * 8 + i;
                float v = 0.f;
                if (k < 64)      v = Whh0[n * 64 + k];
                else if (k < 67) v = Wih0[n * 3 + (k - 64)];
                WfL1[tt][f][i] = (short)f2bf(sca * v);
            }
#pragma unroll
        for (int r = 0; r < 4; ++r) {
            const int nb = r * 64 + 16 * lg + 2 * wq + tt;
            biaL1[tt][r] = ((r == 2) ? P2L2E : NL2E) * (bih0[nb] + bhh0[nb]);
        }
    }
    bf16x8 WfL2[2][4];
    f32x4 biaL2[2];
#pragma unroll
    for (int tt = 0; tt < 2; ++tt) {
        const int n = ga * 64 + 16 * (col >> 2) + 2 * wq + tt;
#pragma unroll
        for (int f = 0; f < 4; ++f)
#pragma unroll
            for (int i = 0; i < 8; ++i) {
                const int k = f * 32 + lg * 8 + i;
                const float v = (k < 64) ? Wih1[n * 64 + k] : Whh1[n * 64 + (k - 64)];
                WfL2[tt][f][i] = (short)f2bf(sca * v);
            }
#pragma unroll
        for (int r = 0; r < 4; ++r) {
            const int nb = r * 64 + 16 * lg + 2 * wq + tt;
            biaL2[tt][r] = ((r == 2) ? P2L2E : NL2E) * (bih1[nb] + bhh1[nb]);
        }
    }
    const int hw = (col * 128 + 32 * lg + 4 * wq) ^ sw;   // same for ring and h2s
    f32x2 C_L1 = {0.f, 0.f};
    f32x2 C_L2 = {0.f, 0.f};
    f32x2 hv01 = {0.f, 0.f};
    bf16x8 pv2 = XQRD(0);

// Merged slot: L1 (t=S) + L2 (t=S-1). Two independent MFMA chains + two
// independent cellupd2 pairs -> intra-wave phase diversity (MFMA/trans/LDS mix).
#define MRG(P, S) do { \
        const char* rb_ = (const char*)ring[P]; \
        const char* hp_ = (const char*)h2s[(P) ^ 1]; \
        bf16x8 v0_ = *(const bf16x8*)(rb_ + rd0); \
        bf16x8 v1_ = *(const bf16x8*)(rb_ + rd1); \
        bf16x8 v2_ = *(const bf16x8*)(hp_ + rd0); \
        bf16x8 v3_ = *(const bf16x8*)(hp_ + rd1); \
        f32x4 b0_ = MM(WfL1[0][2], pv2, biaL1[0]); \
        f32x4 b1_ = MM(WfL1[1][2], pv2, biaL1[1]); \
        b0_ = MM(WfL1[0][0], v0_, b0_); \
        b1_ = MM(WfL1[1][0], v0_, b1_); \
        f32x4 c0_ = MM(WfL2[0][0], v0_, biaL2[0]); \
        f32x4 c1_ = MM(WfL2[1][0], v0_, biaL2[1]); \
        b0_ = MM(WfL1[0][1], v1_, b0_); \
        b1_ = MM(WfL1[1][1], v1_, b1_); \
        pv2 = XQRD((S) + 1); \
        f32x2 hL1_ = cellupd2(b0_, b1_, C_L1); \
        c0_ = MM(WfL2[0][1], v1_, c0_); \
        c1_ = MM(WfL2[1][1], v1_, c1_); \
        c0_ = MM(WfL2[0][2], v2_, c0_); \
        c1_ = MM(WfL2[1][2], v2_, c1_); \
        c0_ = MM(WfL2[0][3], v3_, c0_); \
        c1_ = MM(WfL2[1][3], v3_, c1_); \
        unsigned int p0_; \
        asm("v_cvt_pk_bf16_f32 %0, %1, %2" : "=v"(p0_) : "v"(hL1_.x), "v"(hL1_.y)); \
        *(unsigned int*)((char*)ring[(P) ^ 1] + hw) = p0_; \
        hv01 = cellupd2(c0_, c1_, C_L2); \
        unsigned int p1_; \
        asm("v_cvt_pk_bf16_f32 %0, %1, %2" : "=v"(p1_) : "v"(hv01.x), "v"(hv01.y)); \
        *(unsigned int*)((char*)h2s[P] + hw) = p1_; \
    } while(0)

    // ---- slot 0: L1 only (t=0); ring[1] is zeros ----
    {
        const char* rb_ = (const char*)ring[1];
        bf16x8 v0_ = *(const bf16x8*)(rb_ + rd0);
        bf16x8 v1_ = *(const bf16x8*)(rb_ + rd1);
        f32x4 b0_ = MM(WfL1[0][2], pv2, biaL1[0]);
        f32x4 b1_ = MM(WfL1[1][2], pv2, biaL1[1]);
        b0_ = MM(WfL1[0][0], v0_, b0_);
        b1_ = MM(WfL1[1][0], v0_, b1_);
        b0_ = MM(WfL1[0][1], v1_, b0_);
        b1_ = MM(WfL1[1][1], v1_, b1_);
        pv2 = XQRD(1);
        f32x2 hL1_ = cellupd2(b0_, b1_, C_L1);
        unsigned int p0_;
        asm("v_cvt_pk_bf16_f32 %0, %1, %2" : "=v"(p0_) : "v"(hL1_.x), "v"(hL1_.y));
        *(unsigned int*)((char*)ring[0] + hw) = p0_;
    }
    __syncthreads();                               // end slot 0

#pragma unroll 1
    for (int m = 0; m < 255; ++m) {
        MRG(0, 2 * m + 1);                         // slot 2m+1
        __syncthreads();
        FLUSH(2 * m + 2);
        MRG(1, 2 * m + 2);                         // slot 2m+2
        __syncthreads();
    }
    MRG(0, 511);                                   // slot 511: L1 t=511, L2 t=510
    __syncthreads();

    // ---- slot 512: L2 only (t=511); reads ring[1] (h1_511) + h2s[0] (h2_510) ----
    {
        const char* rb_ = (const char*)ring[1];
        const char* hp_ = (const char*)h2s[0];
        bf16x8 v0_ = *(const bf16x8*)(rb_ + rd0);
        bf16x8 v1_ = *(const bf16x8*)(rb_ + rd1);
        bf16x8 v2_ = *(const bf16x8*)(hp_ + rd0);
        bf16x8 v3_ = *(const bf16x8*)(hp_ + rd1);
        f32x4 c0_ = MM(WfL2[0][0], v0_, biaL2[0]);
        f32x4 c1_ = MM(WfL2[1][0], v0_, biaL2[1]);
        c0_ = MM(WfL2[0][1], v1_, c0_);
        c1_ = MM(WfL2[1][1], v1_, c1_);
        c0_ = MM(WfL2[0][2], v2_, c0_);
        c1_ = MM(WfL2[1][2], v2_, c1_);
        c0_ = MM(WfL2[0][3], v3_, c0_);
        c1_ = MM(WfL2[1][3], v3_, c1_);
        hv01 = cellupd2(c0_, c1_, C_L2);
    }
    const int ub = 16 * lg + 2 * wq;
    h2f[col][ub + 0] = hv01.x;
    h2f[col][ub + 1] = hv01.y;
    __syncthreads();

    // ================= classifier head =================
    {
        const int b = tid & 15, j = tid >> 4;      // j 0..31 over 512 threads
        float s = bc1[j];
#pragma unroll 8
        for (int k = 0; k < 64; ++k) s += Wc1[j * 64 + k] * h2f[b][k];
        hid[b][j] = fmaxf(s, 0.f);
    }
    __syncthreads();
    if (tid < 16) {
        float s = bc2[0];
#pragma unroll 8
        for (int k = 0; k < 32; ++k) s += Wc2[k] * hid[tid][k];
        float e = __builtin_amdgcn_exp2f(NL2E * s);
        out[b0 + tid] = __builtin_amdgcn_rcpf(1.f + e);
    }
}

extern "C" void kernel_launch(void* const* d_in, const int* in_sizes, int n_in,
                              void* d_out, int out_size, void* d_ws, size_t ws_size,
                              hipStream_t stream) {
    lstm2_kernel<<<BATCH / MROWS, 512, 0, stream>>>(
        (const float*)d_in[0],
        (const float*)d_in[1], (const float*)d_in[2],
        (const float*)d_in[3], (const float*)d_in[4],
        (const float*)d_in[5], (const float*)d_in[6],
        (const float*)d_in[7], (const float*)d_in[8],
        (const float*)d_in[9], (const float*)d_in[10],
        (const float*)d_in[11], (const float*)d_in[12],
        (float*)d_out);
}